// Round 12
// baseline (759.880 us; speedup 1.0000x reference)
//
#include <hip/hip_runtime.h>
#include <hip/hip_bf16.h>
#include <stdint.h>

#define N_TOK 2048
#define DM    2048
#define NEXP  64
#define TOPK  4
#define HEXP  512
#define CAPC  512
#define NSH   2
#define HSH   2048
#define RTB   8

typedef __attribute__((ext_vector_type(8))) short short8;
typedef __attribute__((ext_vector_type(4))) float f32x4;
typedef __attribute__((ext_vector_type(4))) float f4;
typedef __attribute__((ext_vector_type(4))) unsigned uint4v;

#define VMWAIT(N) asm volatile("s_waitcnt vmcnt(" #N ")" ::: "memory")
#define LGKM0()   asm volatile("s_waitcnt lgkmcnt(0)" ::: "memory")
#define BARX() do { asm volatile("" ::: "memory");                          \
                    __builtin_amdgcn_s_barrier();                           \
                    asm volatile("" ::: "memory"); } while (0)

static __device__ __forceinline__ unsigned short f2bf(float f) {
  union { float f; unsigned u; } v; v.f = f;
  unsigned r = v.u + 0x7FFFu + ((v.u >> 16) & 1u);   // RNE
  return (unsigned short)(r >> 16);
}

static __device__ __forceinline__ unsigned pk2(float lo, float hi) {
  unsigned u;
  asm("v_cvt_pk_bf16_f32 %0, %1, %2" : "=v"(u) : "v"(lo), "v"(hi));
  return u;
}

// ---------------------------------------------------------------- convert x
__global__ __launch_bounds__(256) void k_convert(const float* __restrict__ x,
                                                 unsigned short* __restrict__ xb) {
  int i = (blockIdx.x * 256 + threadIdx.x) * 8;
  f4 a = *(const f4*)(x + i);
  f4 b = *(const f4*)(x + i + 4);
  short8 o;
  o[0]=f2bf(a[0]); o[1]=f2bf(a[1]); o[2]=f2bf(a[2]); o[3]=f2bf(a[3]);
  o[4]=f2bf(b[0]); o[5]=f2bf(b[1]); o[6]=f2bf(b[2]); o[7]=f2bf(b[3]);
  *(short8*)(xb + i) = o;
}

// ---------------------------------------------------------------- router
#define ARGMAX_ROUND(S,I)                                            \
  { float bv = v; int bi = lane;                                     \
    _Pragma("unroll")                                                \
    for (int o = 32; o; o >>= 1) {                                   \
      float ov = __shfl_xor(bv, o); int oi = __shfl_xor(bi, o);      \
      if (ov > bv || (ov == bv && oi < bi)) { bv = ov; bi = oi; }    \
    }                                                                \
    S = bv; I = bi; if (lane == bi) v = -1.f; }

__global__ __launch_bounds__(256) void k_router(const float* __restrict__ x,
    const float* __restrict__ Wr, const float* __restrict__ bias,
    int* __restrict__ cnt, int* __restrict__ lists, float* __restrict__ wlist) {
  __shared__ float part[4][RTB][64];
  __shared__ float logits[RTB][64];
  int t = threadIdx.x;
  int e = t & 63, sl = t >> 6;
  int tok0 = blockIdx.x * RTB;
  const float* xp = x + (size_t)tok0 * DM;
  float acc[RTB];
#pragma unroll
  for (int i = 0; i < RTB; ++i) acc[i] = 0.f;
  for (int d = sl * 512; d < sl * 512 + 512; ++d) {
    float w = Wr[(size_t)d * NEXP + e];
#pragma unroll
    for (int i = 0; i < RTB; ++i) acc[i] += xp[(size_t)i * DM + d] * w;
  }
#pragma unroll
  for (int i = 0; i < RTB; ++i) part[sl][i][e] = acc[i];
  __syncthreads();
  for (int i = sl; i < RTB; i += 4)
    logits[i][e] = part[0][i][e] + part[1][i][e] + part[2][i][e] + part[3][i][e] + bias[e];
  __syncthreads();
  int lane = t & 63, wv = t >> 6;
  for (int i = wv * 2; i < wv * 2 + 2; ++i) {
    float lg = logits[i][lane];
    float m = lg;
#pragma unroll
    for (int o = 32; o; o >>= 1) m = fmaxf(m, __shfl_xor(m, o));
    float p = expf(lg - m);
    float sm = p;
#pragma unroll
    for (int o = 32; o; o >>= 1) sm += __shfl_xor(sm, o);
    float v = p / sm;
    float s0, s1, s2, s3; int i0, i1, i2, i3;
    ARGMAX_ROUND(s0, i0)
    ARGMAX_ROUND(s1, i1)
    ARGMAX_ROUND(s2, i2)
    ARGMAX_ROUND(s3, i3)
    float tot = s0 + s1 + s2 + s3;
    if (lane < TOPK) {
      float myw = (lane == 0 ? s0 : lane == 1 ? s1 : lane == 2 ? s2 : s3) / tot;
      int   mye = (lane == 0 ? i0 : lane == 1 ? i1 : lane == 2 ? i2 : i3);
      int pos = atomicAdd(&cnt[mye], 1);
      if (pos < CAPC) {
        lists[mye * CAPC + pos] = tok0 + i;
        wlist[mye * CAPC + pos] = myw;
      }
    }
  }
}

// ---------------------------------------------------------------- offsets
__global__ void k_offs(const int* __restrict__ cnt, int* __restrict__ offs) {
  int l = threadIdx.x;
  int c = min(cnt[l], CAPC);
  int sum = c;
#pragma unroll
  for (int o = 1; o < 64; o <<= 1) {
    int ov = __shfl_up(sum, o);
    if (l >= o) sum += ov;
  }
  offs[l + 1] = sum;
  if (l == 0) offs[0] = 0;
}

// ---------------------------------------------------------------- frag helpers (verified)
static __device__ __forceinline__ short8 frag_ldA(const unsigned short* lds, int row, int kElem) {
  int byte = row * 64 + kElem * 2;
  byte ^= ((row >> 1) & 3) << 4;
  return *(const short8*)((const char*)lds + byte);
}

static __device__ __forceinline__ short8 bfragB(const float* lB, int nl, int kb) {
  const float* p = lB + kb * 64 + (nl ^ (((kb >> 3) & 1) << 4));
  float f0 = p[0],   f1 = p[64],  f2 = p[128], f3 = p[192];
  float f4_ = p[256], f5 = p[320], f6 = p[384], f7 = p[448];
  uint4v uv = { pk2(f0, f1), pk2(f2, f3), pk2(f4_, f5), pk2(f6, f7) };
  return __builtin_bit_cast(short8, uv);
}

static __device__ __forceinline__ void mma1f(const unsigned short* lA, const float* lB,
    f32x4 (&acc)[4][2], int wm, int wn, int lane) {
  int r16 = lane & 15;
  int kb  = (lane >> 4) * 8;
  short8 a[4], b[2];
#pragma unroll
  for (int mf = 0; mf < 4; ++mf) a[mf] = frag_ldA(lA, wm + mf * 16 + r16, kb);
#pragma unroll
  for (int nf = 0; nf < 2; ++nf) b[nf] = bfragB(lB, wn + nf * 16 + r16, kb);
#pragma unroll
  for (int mf = 0; mf < 4; ++mf)
#pragma unroll
    for (int nf = 0; nf < 2; ++nf)
      acc[mf][nf] = __builtin_amdgcn_mfma_f32_16x16x32_bf16(a[mf], b[nf], acc[mf][nf], 0, 0, 0);
}

static __device__ __forceinline__ float silu_mul(float g, float u) {
  return g / (1.f + expf(-g)) * u;
}

// ---------------------------------------------------------------- reg-staged engine
// Per thread per K-tile: A = row (tid>>1), two 16B chunks at (tid&1)*2;
//                        B = k-row (tid>>3), two 4-float chunks at (tid&7)*2.
// Loads are LINEAR coalesced; swizzle is applied on the ds_write side and
// matches frag_ldA / bfragB read XORs exactly.
// Depth 4 in regs; 4 vmem ops/phase/wave -> VMWAIT(12) = oldest tile landed.
// Single barrier per phase (writes target the opposite LDS buffer of all
// concurrent readers; barrier sequence makes cross-wave reuse safe).

#define ENG_SETUP()                                                         \
  int tid = threadIdx.x, lane = tid & 63, wv = tid >> 6;                    \
  int wm = (wv >> 1) * 64, wn = (wv & 1) * 32;                              \
  int arow = tid >> 1;                                                      \
  int ac   = (tid & 1) * 2;                                                 \
  int aswz = ((arow >> 1) & 3) << 4;                                        \
  int awb0 = arow * 64 + ((ac * 16) ^ aswz);                                \
  int awb1 = arow * 64 + (((ac + 1) * 16) ^ aswz);                          \
  int bk   = tid >> 3;                                                      \
  int bc   = (tid & 7) * 2;                                                 \
  int bswz = ((bk >> 3) & 1) << 2;                                          \
  int bwb0 = bk * 64 + ((bc ^ bswz) << 2);                                  \
  int bwb1 = bk * 64 + (((bc + 1) ^ bswz) << 2);

#define LOADT(q, t, LDB)                                                    \
  ar0[q] = *(const short8*)(aptr + (size_t)(t) * 32);                       \
  ar1[q] = *(const short8*)(aptr + (size_t)(t) * 32 + 8);                   \
  br0[q] = *(const f4*)(bptr + (size_t)(t) * 32 * (LDB));                   \
  br1[q] = *(const f4*)(bptr + (size_t)(t) * 32 * (LDB) + 4);

#define WRT(q)                                                              \
  *(short8*)((char*)(lA[(q) & 1]) + awb0) = ar0[q];                         \
  *(short8*)((char*)(lA[(q) & 1]) + awb1) = ar1[q];                         \
  *(f4*)(lB[(q) & 1] + bwb0) = br0[q];                                      \
  *(f4*)(lB[(q) & 1] + bwb1) = br1[q];

#define PHS(q, t, LDB)                                                      \
  VMWAIT(12);                                                               \
  WRT(q)                                                                    \
  LGKM0(); BARX();                                                          \
  mma1f(lA[(q) & 1], lB[(q) & 1], acc, wm, wn, lane);                       \
  LOADT(q, (t) + 4, LDB)

#define PHE(q, WN)                                                          \
  VMWAIT(WN);                                                               \
  WRT(q)                                                                    \
  LGKM0(); BARX();                                                          \
  mma1f(lA[(q) & 1], lB[(q) & 1], acc, wm, wn, lane);

#define KLOOP(NT, LDB)                                                      \
  LOADT(0, 0, LDB) LOADT(1, 1, LDB) LOADT(2, 2, LDB) LOADT(3, 3, LDB)       \
  _Pragma("unroll 1")                                                       \
  for (int t = 0; t < (NT) - 4; t += 4) {                                   \
    PHS(0, t, LDB) PHS(1, t + 1, LDB) PHS(2, t + 2, LDB) PHS(3, t + 3, LDB) \
  }                                                                         \
  PHE(0, 12) PHE(1, 8) PHE(2, 4) PHE(3, 0)

// ---------------------------------------------------------------- expert gate/up GEMM
// grid 1024 = (mat 2) x (e 64) x (nb 8); expert blocks XCD-colocated.
__global__ __launch_bounds__(256, 3) void k_mmE(const unsigned short* __restrict__ xbf,
    const float* __restrict__ Wg, const float* __restrict__ Wu,
    const int* __restrict__ cnt, const int* __restrict__ offs,
    const int* __restrict__ lists, unsigned short* __restrict__ hg,
    unsigned short* __restrict__ hu) {
  int bid = blockIdx.x;
  int e   = ((bid & 7) << 3) | ((bid >> 3) & 7);
  int nb  = (bid >> 6) & 7;
  int mat = bid >> 9;
  int n0 = nb * 64;
  int ne = min(cnt[e], CAPC);
  if (ne == 0) return;
  const float* B = (mat ? Wu : Wg) + (size_t)e * DM * HEXP;
  unsigned short* hdst = mat ? hu : hg;
  const int* lst = lists + e * CAPC;
  int base = offs[e];
  __shared__ unsigned short lA[2][128 * 32];
  __shared__ float lB[2][32 * 64];
  ENG_SETUP()
  const float* bptr = B + (size_t)bk * HEXP + n0 + bc * 4;
  short8 ar0[4], ar1[4]; f4 br0[4], br1[4];
  for (int m0 = 0; m0 < ne; m0 += 128) {
    int srow = lst[min(m0 + arow, ne - 1)];
    const unsigned short* aptr = xbf + (size_t)srow * DM + ac * 8;
    f32x4 acc[4][2] = {};
    KLOOP(64, HEXP)
#pragma unroll
    for (int mf = 0; mf < 4; ++mf)
#pragma unroll
      for (int r = 0; r < 4; ++r) {
        int rl = m0 + wm + mf * 16 + (lane >> 4) * 4 + r;
        if (rl < ne) {
#pragma unroll
          for (int nf = 0; nf < 2; ++nf) {
            int col = n0 + wn + nf * 16 + (lane & 15);
            hdst[(size_t)(base + rl) * HEXP + col] = f2bf(acc[mf][nf][r]);
          }
        }
      }
  }
}

// ---------------------------------------------------------------- expert swiglu
__global__ __launch_bounds__(256) void k_swiglu_e(const unsigned short* __restrict__ hg,
    const unsigned short* __restrict__ hu, const int* __restrict__ offs,
    unsigned short* __restrict__ hws) {
  int total = offs[NEXP];
  int gid = blockIdx.x * 256 + threadIdx.x;
  int row = gid >> 6;
  if (row >= total) return;
  int c0 = (gid & 63) * 8;
  size_t o = (size_t)row * HEXP + c0;
  short8 g8 = *(const short8*)(hg + o);
  short8 u8 = *(const short8*)(hu + o);
  short8 r;
#pragma unroll
  for (int j = 0; j < 8; ++j) {
    union { unsigned u; float f; } gg, uu;
    gg.u = ((unsigned)(unsigned short)g8[j]) << 16;
    uu.u = ((unsigned)(unsigned short)u8[j]) << 16;
    r[j] = f2bf(silu_mul(gg.f, uu.f));
  }
  *(short8*)(hws + o) = r;
}

// ---------------------------------------------------------------- shared gate/up GEMM
// grid 2048 = (mat 2) x (s 2) x (mb 16) x (nb 32)
__global__ __launch_bounds__(256, 3) void k_mmS(const unsigned short* __restrict__ xbf,
    const float* __restrict__ Sg, const float* __restrict__ Su,
    unsigned short* __restrict__ hsg, unsigned short* __restrict__ hsu) {
  int bid = blockIdx.x;
  int nb = bid & 31, mb = (bid >> 5) & 15, s = (bid >> 9) & 1, mat = bid >> 10;
  int n0 = nb * 64, m0 = mb * 128;
  const float* B = (mat ? Su : Sg) + (size_t)s * DM * HSH;
  unsigned short* hdst = mat ? hsu : hsg;
  __shared__ unsigned short lA[2][128 * 32];
  __shared__ float lB[2][32 * 64];
  ENG_SETUP()
  const float* bptr = B + (size_t)bk * HSH + n0 + bc * 4;
  const unsigned short* aptr = xbf + (size_t)(m0 + arow) * DM + ac * 8;
  short8 ar0[4], ar1[4]; f4 br0[4], br1[4];
  f32x4 acc[4][2] = {};
  KLOOP(64, HSH)
#pragma unroll
  for (int mf = 0; mf < 4; ++mf)
#pragma unroll
    for (int nf = 0; nf < 2; ++nf)
#pragma unroll
      for (int r = 0; r < 4; ++r) {
        int row = m0 + wm + mf * 16 + (lane >> 4) * 4 + r;
        int col = n0 + wn + nf * 16 + (lane & 15);
        hdst[(size_t)row * (NSH * HSH) + s * HSH + col] = f2bf(acc[mf][nf][r]);
      }
}

// ---------------------------------------------------------------- shared swiglu
__global__ __launch_bounds__(256) void k_swiglu_s(const unsigned short* __restrict__ hsg,
    const unsigned short* __restrict__ hsu, unsigned short* __restrict__ hs) {
  int gid = blockIdx.x * 256 + threadIdx.x;
  size_t o = (size_t)gid * 8;
  short8 g8 = *(const short8*)(hsg + o);
  short8 u8 = *(const short8*)(hsu + o);
  short8 r;
#pragma unroll
  for (int j = 0; j < 8; ++j) {
    union { unsigned u; float f; } gg, uu;
    gg.u = ((unsigned)(unsigned short)g8[j]) << 16;
    uu.u = ((unsigned)(unsigned short)u8[j]) << 16;
    r[j] = f2bf(silu_mul(gg.f, uu.f));
  }
  *(short8*)(hs + o) = r;
}

// ---------------------------------------------------------------- shared down (writes out)
// grid 512 = (mb 16) x (nb 32), K = 4096
__global__ __launch_bounds__(256, 3) void k_sd4(const unsigned short* __restrict__ hs,
    const float* __restrict__ Sd, float* __restrict__ out) {
  int bid = blockIdx.x;
  int nb = bid & 31, mb = bid >> 5;
  int n0 = nb * 64, m0 = mb * 128;
  __shared__ unsigned short lA[2][128 * 32];
  __shared__ float lB[2][32 * 64];
  ENG_SETUP()
  const float* bptr = Sd + (size_t)bk * DM + n0 + bc * 4;
  const unsigned short* aptr = hs + (size_t)(m0 + arow) * (NSH * HSH) + ac * 8;
  short8 ar0[4], ar1[4]; f4 br0[4], br1[4];
  f32x4 acc[4][2] = {};
  KLOOP(128, DM)
#pragma unroll
  for (int mf = 0; mf < 4; ++mf)
#pragma unroll
    for (int nf = 0; nf < 2; ++nf)
#pragma unroll
      for (int r = 0; r < 4; ++r) {
        int row = m0 + wm + mf * 16 + (lane >> 4) * 4 + r;
        int col = n0 + wn + nf * 16 + (lane & 15);
        out[(size_t)row * DM + col] = acc[mf][nf][r];
      }
}

// ---------------------------------------------------------------- expert down (atomic add)
// grid 2048 = (e 64) x (nb 32), e XCD-colocated
__global__ __launch_bounds__(256, 3) void k_downE(const unsigned short* __restrict__ hws,
    const float* __restrict__ Wd, const int* __restrict__ cnt, const int* __restrict__ offs,
    const int* __restrict__ lists, const float* __restrict__ wlist,
    float* __restrict__ out) {
  int bid = blockIdx.x;
  int e  = ((bid & 7) << 3) | ((bid >> 3) & 7);
  int nb = bid >> 6;
  int n0 = nb * 64;
  int ne = min(cnt[e], CAPC);
  if (ne == 0) return;
  const float* B = Wd + (size_t)e * HEXP * DM;
  const unsigned short* Abase = hws + (size_t)offs[e] * HEXP;
  __shared__ unsigned short lA[2][128 * 32];
  __shared__ float lB[2][32 * 64];
  ENG_SETUP()
  const float* bptr = B + (size_t)bk * DM + n0 + bc * 4;
  short8 ar0[4], ar1[4]; f4 br0[4], br1[4];
  for (int m0 = 0; m0 < ne; m0 += 128) {
    const unsigned short* aptr = Abase + (size_t)min(m0 + arow, ne - 1) * HEXP + ac * 8;
    f32x4 acc[4][2] = {};
    KLOOP(16, DM)
#pragma unroll
    for (int mf = 0; mf < 4; ++mf)
#pragma unroll
      for (int r = 0; r < 4; ++r) {
        int rl = m0 + wm + mf * 16 + (lane >> 4) * 4 + r;
        if (rl < ne) {
          int tok  = lists[e * CAPC + rl];
          float w  = wlist[e * CAPC + rl];
#pragma unroll
          for (int nf = 0; nf < 2; ++nf) {
            int col = n0 + wn + nf * 16 + (lane & 15);
            atomicAdd(out + (size_t)tok * DM + col, acc[mf][nf][r] * w);
          }
        }
      }
  }
}

// ---------------------------------------------------------------- launch
extern "C" void kernel_launch(void* const* d_in, const int* in_sizes, int n_in,
                              void* d_out, int out_size, void* d_ws, size_t ws_size,
                              hipStream_t stream) {
  const float* x    = (const float*)d_in[0];
  const float* Wr   = (const float*)d_in[1];
  const float* bias = (const float*)d_in[2];
  const float* Wg   = (const float*)d_in[3];
  const float* Wu   = (const float*)d_in[4];
  const float* Wd   = (const float*)d_in[5];
  const float* Sg   = (const float*)d_in[6];
  const float* Su   = (const float*)d_in[7];
  const float* Sd   = (const float*)d_in[8];
  float* out = (float*)d_out;
  char* ws = (char*)d_ws;

  const size_t off_cnt   = 0;
  const size_t off_offs  = 256;
  const size_t off_lists = 1024;
  const size_t off_wlist = off_lists + (size_t)NEXP * CAPC * 4;
  const size_t off_xbf   = off_wlist + (size_t)NEXP * CAPC * 4;
  const size_t off_hs    = off_xbf + (size_t)N_TOK * DM * 2;
  const size_t off_hws   = off_hs + (size_t)N_TOK * NSH * HSH * 2;
  const size_t off_hg    = off_hws + (size_t)N_TOK * TOPK * HEXP * 2;
  const size_t off_hu    = off_hg + (size_t)N_TOK * TOPK * HEXP * 2;
  const size_t off_hsg   = off_hu + (size_t)N_TOK * TOPK * HEXP * 2;
  const size_t off_hsu   = off_hsg + (size_t)N_TOK * NSH * HSH * 2;
  const size_t req       = off_hsu + (size_t)N_TOK * NSH * HSH * 2;
  if (ws_size < req) return;

  int* cnt            = (int*)(ws + off_cnt);
  int* offs           = (int*)(ws + off_offs);
  int* lists          = (int*)(ws + off_lists);
  float* wlist        = (float*)(ws + off_wlist);
  unsigned short* xbf = (unsigned short*)(ws + off_xbf);
  unsigned short* hs  = (unsigned short*)(ws + off_hs);
  unsigned short* hws = (unsigned short*)(ws + off_hws);
  unsigned short* hg  = (unsigned short*)(ws + off_hg);
  unsigned short* hu  = (unsigned short*)(ws + off_hu);
  unsigned short* hsg = (unsigned short*)(ws + off_hsg);
  unsigned short* hsu = (unsigned short*)(ws + off_hsu);

  hipMemsetAsync(cnt, 0, NEXP * sizeof(int), stream);
  k_convert<<<(N_TOK * DM) / (256 * 8), 256, 0, stream>>>(x, xbf);
  k_router<<<N_TOK / RTB, 256, 0, stream>>>(x, Wr, bias, cnt, lists, wlist);
  k_offs<<<1, 64, 0, stream>>>(cnt, offs);

  k_mmE<<<1024, 256, 0, stream>>>(xbf, Wg, Wu, cnt, offs, lists, hg, hu);
  k_swiglu_e<<<(N_TOK * TOPK * HEXP / 8) / 256, 256, 0, stream>>>(hg, hu, offs, hws);

  k_mmS<<<2048, 256, 0, stream>>>(xbf, Sg, Su, hsg, hsu);
  k_swiglu_s<<<(N_TOK * NSH * HSH / 8) / 256, 256, 0, stream>>>(hsg, hsu, hs);

  k_sd4<<<512, 256, 0, stream>>>(hs, Sd, out);
  k_downE<<<2048, 256, 0, stream>>>(hws, Wd, cnt, offs, lists, wlist, out);
}